// Round 1
// baseline (513.587 us; speedup 1.0000x reference)
//
#include <hip/hip_runtime.h>

#define KDIM 512
#define NDIM 512
#define ATT  196
#define NB   1024

typedef __attribute__((ext_vector_type(8))) short bf16x8;
typedef __attribute__((ext_vector_type(8))) unsigned short ushort8;
typedef __attribute__((ext_vector_type(4))) float f32x4;

__device__ __forceinline__ float fast_tanh(float x) {
    x = fminf(15.f, fmaxf(-15.f, x));
    float t = __expf(2.f * x);
    return (t - 1.f) / (t + 1.f);
}

__device__ __forceinline__ unsigned short f2bf(float x) {
    union { float f; unsigned u; } v; v.f = x;
    unsigned r = v.u + 0x7FFF + ((v.u >> 16) & 1);   // RNE
    return (unsigned short)(r >> 16);
}

// ---------------------------------------------------------------------------
// Pre-convert 6 weight matrices [512][512] f32 (k-major) into bf16 tiled
// layout per weight: [kt(16)][n(512)][kc'(4)][e(8)] where kc = kc' ^ (n&3)
// holds W[kt*32 + kc*8 + e][n]. This bakes the LDS bank swizzle so GEMM
// B-staging is a pure linear copy and frag ds_read_b128 is ~conflict-free.
// ---------------------------------------------------------------------------
__global__ void prep_weights(const float* __restrict__ W0, const float* __restrict__ W1,
                             const float* __restrict__ W2, const float* __restrict__ W3,
                             const float* __restrict__ W4, const float* __restrict__ W5,
                             unsigned short* __restrict__ Wt) {
    int gid = blockIdx.x * 256 + threadIdx.x;   // one thread per 16B chunk; 196608 total
    int w   = gid >> 15;
    int r   = gid & 32767;
    int kt  = r >> 11;
    int c   = r & 2047;
    int n   = c >> 2;
    int kcp = c & 3;
    int kc  = kcp ^ (n & 3);
    const float* W = (w == 0) ? W0 : (w == 1) ? W1 : (w == 2) ? W2 :
                     (w == 3) ? W3 : (w == 4) ? W4 : W5;
    int k0 = kt * 32 + kc * 8;
    ushort8 v;
#pragma unroll
    for (int e = 0; e < 8; ++e) v[e] = f2bf(W[(size_t)(k0 + e) * NDIM + n]);
    *(ushort8*)&Wt[((size_t)w * 32768 + r) * 8] = v;
}

// ---------------------------------------------------------------------------
// Generic GEMM: C[M,512] = A[M,512](f32) @ W(bf16 tiled) ; epilogues:
//  EPI_RELU/TANH/NONE: out[row,col] = act(acc + bias[col])
//  EPI_SCORE: score[b*197 + (row - b*DIVR) + ADDI] =
//             sum_col tanh(acc + bias[col] + h_emb[b,col]) * Walpha[col]
// BM=128, BN=512 (full), BK=32, 512 threads = 8 waves (2 M x 4 N),
// wave tile 64x128, mfma_f32_16x16x32_bf16.
// ---------------------------------------------------------------------------
#define EPI_RELU  0
#define EPI_TANH  1
#define EPI_NONE  2
#define EPI_SCORE 3

template<int EPI, int DIVR, int ADDI>
__launch_bounds__(512, 2)
__global__ void gemm512(const float* __restrict__ A, const unsigned short* __restrict__ Wt,
                        const float* __restrict__ bias, float* __restrict__ out,
                        const float* __restrict__ h_emb, const float* __restrict__ Walpha) {
    __shared__ unsigned short A_lds[2][128 * 32];
    __shared__ unsigned short B_lds[2][512 * 32];
    __shared__ float s_red[4][128];

    const int tid  = threadIdx.x;
    const int gm0  = blockIdx.x * 128;
    const int wid  = tid >> 6, lane = tid & 63;
    const int wm   = wid >> 2, wn = wid & 3;
    const int lr   = lane & 15, lk = lane >> 4;
    const int swk  = ((lk ^ (lr & 3)) << 3);   // swizzled k-chunk offset (ushorts)

    // staging mapping: thread t -> row=t/4, kc=t%4 (8 f32 -> one 16B bf16 chunk)
    const int srow = tid >> 2, skc = tid & 3;
    const float* aptr = A + (size_t)(gm0 + srow) * KDIM + skc * 8;
    const int a_off = srow * 32 + (((skc ^ (srow & 3))) << 3);

    f32x4 acc[4][8] = {};

    auto stage = [&](int kt, int buf) {
        float4 x0 = *(const float4*)(aptr + kt * 32);
        float4 x1 = *(const float4*)(aptr + kt * 32 + 4);
        ushort8 av;
        av[0] = f2bf(x0.x); av[1] = f2bf(x0.y); av[2] = f2bf(x0.z); av[3] = f2bf(x0.w);
        av[4] = f2bf(x1.x); av[5] = f2bf(x1.y); av[6] = f2bf(x1.z); av[7] = f2bf(x1.w);
        *(ushort8*)&A_lds[buf][a_off] = av;
        const ushort8* src = (const ushort8*)(Wt + (size_t)kt * 16384);
        ushort8* dst = (ushort8*)&B_lds[buf][0];
        dst[tid]        = src[tid];
        dst[tid + 512]  = src[tid + 512];
        dst[tid + 1024] = src[tid + 1024];
        dst[tid + 1536] = src[tid + 1536];
    };

    stage(0, 0);
    __syncthreads();

    for (int kt = 0; kt < 16; ++kt) {
        const int buf = kt & 1;
        if (kt < 15) stage(kt + 1, buf ^ 1);

        bf16x8 af[4], bfr[8];
#pragma unroll
        for (int m = 0; m < 4; ++m) {
            int row = wm * 64 + m * 16 + lr;
            af[m] = *(const bf16x8*)&A_lds[buf][row * 32 + swk];
        }
#pragma unroll
        for (int n = 0; n < 8; ++n) {
            int col = wn * 128 + n * 16 + lr;
            bfr[n] = *(const bf16x8*)&B_lds[buf][col * 32 + swk];
        }
#pragma unroll
        for (int m = 0; m < 4; ++m)
#pragma unroll
            for (int n = 0; n < 8; ++n)
                acc[m][n] = __builtin_amdgcn_mfma_f32_16x16x32_bf16(af[m], bfr[n], acc[m][n], 0, 0, 0);
        __syncthreads();
    }

    if constexpr (EPI == EPI_SCORE) {
        float wa[8], bs[8];
        int cols[8];
#pragma unroll
        for (int n = 0; n < 8; ++n) {
            cols[n] = wn * 128 + n * 16 + lr;
            bs[n] = bias[cols[n]];
            wa[n] = Walpha[cols[n]];
        }
#pragma unroll
        for (int m = 0; m < 4; ++m) {
#pragma unroll
            for (int r = 0; r < 4; ++r) {
                int rloc = wm * 64 + m * 16 + lk * 4 + r;
                int rg = gm0 + rloc;
                int bb = rg / DIVR;
                const float* he = h_emb + (size_t)bb * NDIM;
                float sum = 0.f;
#pragma unroll
                for (int n = 0; n < 8; ++n)
                    sum += fast_tanh(acc[m][n][r] + bs[n] + he[cols[n]]) * wa[n];
                sum += __shfl_xor(sum, 1);
                sum += __shfl_xor(sum, 2);
                sum += __shfl_xor(sum, 4);
                sum += __shfl_xor(sum, 8);
                if (lr == 0) s_red[wn][rloc] = sum;
            }
        }
        __syncthreads();
        if (tid < 128) {
            float s2 = s_red[0][tid] + s_red[1][tid] + s_red[2][tid] + s_red[3][tid];
            int rg = gm0 + tid;
            int bb = rg / DIVR;
            out[(size_t)bb * 197 + (rg - bb * DIVR) + ADDI] = s2;
        }
    } else {
#pragma unroll
        for (int m = 0; m < 4; ++m)
#pragma unroll
            for (int n = 0; n < 8; ++n) {
                int col = wn * 128 + n * 16 + lr;
#pragma unroll
                for (int r = 0; r < 4; ++r) {
                    int row = gm0 + wm * 64 + m * 16 + lk * 4 + r;
                    float v = acc[m][n][r] + bias[col];
                    if constexpr (EPI == EPI_RELU) v = fmaxf(v, 0.f);
                    if constexpr (EPI == EPI_TANH) v = fast_tanh(v);
                    out[(size_t)row * NDIM + col] = v;
                }
            }
    }
}

// ---------------------------------------------------------------------------
// Per-batch: softmax over 197 scores, then
// atten_out[b,:] = alpha0*sent_lin[b,:] + sum_s alpha[s+1]*att[b,s,:] + h_lin[b,:]
// ---------------------------------------------------------------------------
__global__ __launch_bounds__(256) void softmax_chat(
        const float* __restrict__ score, const float* __restrict__ sent_lin,
        const float* __restrict__ h_lin, const float* __restrict__ att,
        float* __restrict__ atten_out) {
    int b = blockIdx.x, tid = threadIdx.x;
    __shared__ float al[200];
    __shared__ float rmax[4], rsum[4];

    float v = (tid < 197) ? score[b * 197 + tid] : -1e30f;
    float m = v;
#pragma unroll
    for (int o = 32; o; o >>= 1) m = fmaxf(m, __shfl_xor(m, o));
    if ((tid & 63) == 0) rmax[tid >> 6] = m;
    __syncthreads();
    m = fmaxf(fmaxf(rmax[0], rmax[1]), fmaxf(rmax[2], rmax[3]));
    float e = (tid < 197) ? __expf(v - m) : 0.f;
    float s = e;
#pragma unroll
    for (int o = 32; o; o >>= 1) s += __shfl_xor(s, o);
    if ((tid & 63) == 0) rsum[tid >> 6] = s;
    __syncthreads();
    s = rsum[0] + rsum[1] + rsum[2] + rsum[3];
    if (tid < 197) al[tid] = e / s;
    __syncthreads();

    const float2* af = (const float2*)(att + (size_t)b * ATT * KDIM);
    float2 a0 = ((const float2*)(sent_lin + (size_t)b * KDIM))[tid];
    float w0 = al[0];
    float2 accv; accv.x = w0 * a0.x; accv.y = w0 * a0.y;
#pragma unroll 4
    for (int ss = 0; ss < ATT; ++ss) {
        float w = al[ss + 1];
        float2 x = af[(size_t)ss * 256 + tid];
        accv.x += w * x.x; accv.y += w * x.y;
    }
    float2 hl = ((const float2*)(h_lin + (size_t)b * KDIM))[tid];
    accv.x += hl.x; accv.y += hl.y;
    ((float2*)(atten_out + (size_t)b * KDIM))[tid] = accv;
}

// ---------------------------------------------------------------------------
extern "C" void kernel_launch(void* const* d_in, const int* in_sizes, int n_in,
                              void* d_out, int out_size, void* d_ws, size_t ws_size,
                              hipStream_t stream) {
    const float* h     = (const float*)d_in[0];
    const float* sent  = (const float*)d_in[1];
    const float* att   = (const float*)d_in[2];
    const float* W_ctx = (const float*)d_in[3];
    const float* b_ctx = (const float*)d_in[4];
    const float* W_sl  = (const float*)d_in[5];
    const float* b_sl  = (const float*)d_in[6];
    const float* W_se  = (const float*)d_in[7];
    const float* b_se  = (const float*)d_in[8];
    const float* W_hl  = (const float*)d_in[9];
    const float* b_hl  = (const float*)d_in[10];
    const float* W_he  = (const float*)d_in[11];
    const float* b_he  = (const float*)d_in[12];
    const float* W_al  = (const float*)d_in[13];
    // d_in[14] = b_alpha: constant shift across positions, cancels in softmax
    const float* W_a2h = (const float*)d_in[15];
    const float* b_a2h = (const float*)d_in[16];
    float* out = (float*)d_out;

    char* ws = (char*)d_ws;
    unsigned short* Wt = (unsigned short*)ws;                 // 6 * 512KB bf16 tiled = 3MB
    float* sent_lin = (float*)(ws + 6u * 512 * 1024);
    float* h_lin    = sent_lin + (size_t)NB * 512;
    float* h_emb    = h_lin    + (size_t)NB * 512;
    float* scorebuf = h_emb    + (size_t)NB * 512;            // 1024*197
    float* atten    = scorebuf + (size_t)NB * 197;

    const size_t WSZ = 512 * 512;  // ushorts per weight
    // weight order in Wt: 0=W_sl 1=W_hl 2=W_he 3=W_ctx 4=W_a2h 5=W_se
    prep_weights<<<768, 256, 0, stream>>>(W_sl, W_hl, W_he, W_ctx, W_a2h, W_se, Wt);

    gemm512<EPI_RELU, 1, 0><<<NB / 128, 512, 0, stream>>>(sent, Wt + 0 * WSZ, b_sl, sent_lin, nullptr, nullptr);
    gemm512<EPI_TANH, 1, 0><<<NB / 128, 512, 0, stream>>>(h,    Wt + 1 * WSZ, b_hl, h_lin,    nullptr, nullptr);
    gemm512<EPI_NONE, 1, 0><<<NB / 128, 512, 0, stream>>>(h_lin, Wt + 2 * WSZ, b_he, h_emb,   nullptr, nullptr);
    // sentinel score -> scorebuf[b*197 + 0]
    gemm512<EPI_SCORE, 1, 0><<<NB / 128, 512, 0, stream>>>(sent_lin, Wt + 5 * WSZ, b_se, scorebuf, h_emb, W_al);
    // visual scores -> scorebuf[b*197 + 1 + s]   (M = 1024*196 = 200704)
    gemm512<EPI_SCORE, 196, 1><<<(NB * ATT) / 128, 512, 0, stream>>>(att, Wt + 3 * WSZ, b_ctx, scorebuf, h_emb, W_al);

    softmax_chat<<<NB, 256, 0, stream>>>(scorebuf, sent_lin, h_lin, att, atten);

    gemm512<EPI_TANH, 1, 0><<<NB / 128, 512, 0, stream>>>(atten, Wt + 4 * WSZ, b_a2h, out, nullptr, nullptr);
}